// Round 6
// baseline (481.724 us; speedup 1.0000x reference)
//
#include <hip/hip_runtime.h>
#include <math.h>

#define NN 50000
#define EE 800000
#define FIN 100
#define HH 64
#define CC 18
#define TB 782          // ceil(NN/64) gemm/mlp tile blocks
#define CNTB 512        // count blocks appended to fat kernel
#define RPB 49          // ceil(NN/1024) rowptr blocks

// ---- fat kernel: blocks [0,TB) do p = x@fW1 tile GEMM; [TB,TB+CNTB) count --
__global__ __launch_bounds__(256) void k_gemm_count(
    const float* __restrict__ x, const float* __restrict__ W,
    float* __restrict__ p, const int* __restrict__ ei,
    int* __restrict__ counts) {
  __shared__ float smem[FIN * HH + 64 * FIN];  // Ws | xs, 51.2 KB
  int t = threadIdx.x;
  if (blockIdx.x >= TB) {
    int bb = blockIdx.x - TB;
    for (int e = bb * 256 + t; e < EE; e += CNTB * 256)
      atomicAdd(&counts[ei[EE + e]], 1);
    return;
  }
  float* Ws = smem;
  float* xs = smem + FIN * HH;
  for (int i = t; i < FIN * HH; i += 256) Ws[i] = W[i];
  int n0 = blockIdx.x * 64;
  for (int i = t; i < 64 * FIN; i += 256) {
    int r = i / FIN, c = i - r * FIN;
    int n = n0 + r;
    xs[i] = (n < NN) ? x[n * FIN + c] : 0.f;
  }
  __syncthreads();
  int j = t & 63, nl = t >> 6;
  float acc[16];
#pragma unroll
  for (int q = 0; q < 16; ++q) acc[q] = 0.f;
  for (int k4 = 0; k4 < FIN / 4; ++k4) {
    float w0 = Ws[(k4 * 4 + 0) * HH + j];
    float w1 = Ws[(k4 * 4 + 1) * HH + j];
    float w2 = Ws[(k4 * 4 + 2) * HH + j];
    float w3 = Ws[(k4 * 4 + 3) * HH + j];
#pragma unroll
    for (int q = 0; q < 16; ++q) {
      float4 z =
          *reinterpret_cast<const float4*>(xs + (nl + q * 4) * FIN + k4 * 4);
      acc[q] = fmaf(z.x, w0, acc[q]);
      acc[q] = fmaf(z.y, w1, acc[q]);
      acc[q] = fmaf(z.z, w2, acc[q]);
      acc[q] = fmaf(z.w, w3, acc[q]);
    }
  }
#pragma unroll
  for (int q = 0; q < 16; ++q) {
    int n = n0 + nl + q * 4;
    if (n < NN) p[n * HH + j] = acc[q];
  }
}

__device__ __forceinline__ void load4_guard(const int* __restrict__ a, int i4,
                                            int& c0, int& c1, int& c2,
                                            int& c3) {
  if (i4 + 3 < NN) {
    int4 v = *reinterpret_cast<const int4*>(a + i4);
    c0 = v.x; c1 = v.y; c2 = v.z; c3 = v.w;
  } else {
    c0 = (i4 < NN) ? a[i4] : 0;
    c1 = (i4 + 1 < NN) ? a[i4 + 1] : 0;
    c2 = (i4 + 2 < NN) ? a[i4 + 2] : 0;
    c3 = (i4 + 3 < NN) ? a[i4 + 3] : 0;
  }
}

// ---- rowptr: each block self-computes its base by summing preceding counts
__global__ __launch_bounds__(256) void k_rowptr(const int* __restrict__ counts,
                                                int* __restrict__ rowptr,
                                                int* __restrict__ cursor) {
  __shared__ int wtot[4];
  __shared__ int sbase;
  int t = threadIdx.x, lane = t & 63, wid = t >> 6;
  int lim = blockIdx.x * 1024;
  int s = 0;
  for (int i = t; i < lim; i += 256) s += counts[i];
#pragma unroll
  for (int m = 32; m >= 1; m >>= 1) s += __shfl_xor(s, m);
  if (lane == 0) wtot[wid] = s;
  __syncthreads();
  if (t == 0) sbase = wtot[0] + wtot[1] + wtot[2] + wtot[3];
  __syncthreads();
  int base0 = sbase;
  int i4 = blockIdx.x * 1024 + t * 4;
  int c0, c1, c2, c3;
  load4_guard(counts, i4, c0, c1, c2, c3);
  int sl = c0 + c1 + c2 + c3;
  int x = sl;
#pragma unroll
  for (int off = 1; off < 64; off <<= 1) {
    int y = __shfl_up(x, off);
    if (lane >= off) x += y;
  }
  __syncthreads();  // wtot reuse
  if (lane == 63) wtot[wid] = x;
  __syncthreads();
  int base = base0;
  for (int w = 0; w < wid; ++w) base += wtot[w];
  int pr = base + x - sl;
  int p0 = pr, p1 = p0 + c0, p2 = p1 + c1, p3 = p2 + c2;
  if (i4 + 3 < NN) {
    *reinterpret_cast<int4*>(rowptr + i4) = make_int4(p0, p1, p2, p3);
    *reinterpret_cast<int4*>(cursor + i4) = make_int4(p0, p1, p2, p3);
  } else {
    if (i4 < NN) { rowptr[i4] = p0; cursor[i4] = p0; }
    if (i4 + 1 < NN) { rowptr[i4 + 1] = p1; cursor[i4 + 1] = p1; }
    if (i4 + 2 < NN) { rowptr[i4 + 2] = p2; cursor[i4 + 2] = p2; }
  }
  if (i4 + 4 == NN) rowptr[NN] = p3 + c3;
}

// ---- fill: eidx[pos] = src, pos from per-dst cursor ----------------------
__global__ __launch_bounds__(256) void k_fill(const int* __restrict__ ei,
                                              int* __restrict__ cursor,
                                              int* __restrict__ eidx) {
  int e4 = (blockIdx.x * 256 + threadIdx.x) * 4;
  if (e4 >= EE) return;
  int4 sv = *reinterpret_cast<const int4*>(ei + e4);
  int4 dv = *reinterpret_cast<const int4*>(ei + EE + e4);
  eidx[atomicAdd(&cursor[dv.x], 1)] = sv.x;
  eidx[atomicAdd(&cursor[dv.y], 1)] = sv.y;
  eidx[atomicAdd(&cursor[dv.z], 1)] = sv.z;
  eidx[atomicAdd(&cursor[dv.w], 1)] = sv.w;
}

// ---- gather: 16 lanes per node; agg[n][:] = sum feat[src][:] -------------
__global__ __launch_bounds__(256) void k_gather(
    const float* __restrict__ feat, const int* __restrict__ rowptr,
    const int* __restrict__ eidx, float* __restrict__ agg) {
  int t = threadIdx.x;
  int grp = t >> 4, c4 = t & 15;
  int n = blockIdx.x * 16 + grp;
  if (n >= NN) return;
  int beg = rowptr[n], end = rowptr[n + 1];
  float ax = 0.f, ay = 0.f, az = 0.f, aw = 0.f;
  int i = beg;
  for (; i + 4 <= end; i += 4) {
    int s0 = eidx[i], s1 = eidx[i + 1], s2 = eidx[i + 2], s3 = eidx[i + 3];
    float4 v0 = *reinterpret_cast<const float4*>(feat + s0 * HH + c4 * 4);
    float4 v1 = *reinterpret_cast<const float4*>(feat + s1 * HH + c4 * 4);
    float4 v2 = *reinterpret_cast<const float4*>(feat + s2 * HH + c4 * 4);
    float4 v3 = *reinterpret_cast<const float4*>(feat + s3 * HH + c4 * 4);
    ax += (v0.x + v1.x) + (v2.x + v3.x);
    ay += (v0.y + v1.y) + (v2.y + v3.y);
    az += (v0.z + v1.z) + (v2.z + v3.z);
    aw += (v0.w + v1.w) + (v2.w + v3.w);
  }
  for (; i < end; ++i) {
    int s0 = eidx[i];
    float4 v0 = *reinterpret_cast<const float4*>(feat + s0 * HH + c4 * 4);
    ax += v0.x; ay += v0.y; az += v0.z; aw += v0.w;
  }
  *reinterpret_cast<float4*>(agg + n * HH + c4 * 4) =
      make_float4(ax, ay, az, aw);
}

// ---- tile GEMM helper: acc[q] (16 rows x col j) += Zs(rows) @ Ws(col j) ---
__device__ __forceinline__ void tile_gemm(const float* __restrict__ Zs,
                                          const float* __restrict__ Ws,
                                          int nl, int j, float* acc) {
  const float4* Zv = reinterpret_cast<const float4*>(Zs);
  for (int k4 = 0; k4 < 16; ++k4) {
    float w0 = Ws[(k4 * 4 + 0) * HH + j];
    float w1 = Ws[(k4 * 4 + 1) * HH + j];
    float w2 = Ws[(k4 * 4 + 2) * HH + j];
    float w3 = Ws[(k4 * 4 + 3) * HH + j];
#pragma unroll
    for (int q = 0; q < 16; ++q) {
      float4 z = Zv[(nl + q * 4) * 16 + k4];
      acc[q] = fmaf(z.x, w0, acc[q]);
      acc[q] = fmaf(z.y, w1, acc[q]);
      acc[q] = fmaf(z.z, w2, acc[q]);
      acc[q] = fmaf(z.w, w3, acc[q]);
    }
  }
}

// -------- first conv MLP tile: T=relu((1+e)p+agg+b1); out=BN(relu(T@W2+b2))
__global__ __launch_bounds__(256) void k_mlp_first(
    const float* __restrict__ p, const float* __restrict__ agg,
    const float* __restrict__ epsv, const float* __restrict__ b1,
    const float* __restrict__ W2, const float* __restrict__ b2,
    const float* __restrict__ g, const float* __restrict__ be,
    const float* __restrict__ mu, const float* __restrict__ var,
    float* __restrict__ out) {
  __shared__ float Zs[HH * HH];
  __shared__ float W2s[HH * HH];
  int t = threadIdx.x;
  int n0 = blockIdx.x * 64;
  float e0 = 1.f + epsv[0];
  for (int i4 = t * 4; i4 < HH * HH; i4 += 1024)
    *reinterpret_cast<float4*>(W2s + i4) =
        *reinterpret_cast<const float4*>(W2 + i4);
  for (int i4 = t * 4; i4 < HH * HH; i4 += 1024) {
    int gw = n0 * HH + i4;
    float4 z4 = make_float4(0.f, 0.f, 0.f, 0.f);
    if (gw < NN * HH) {
      float4 pv = *reinterpret_cast<const float4*>(p + gw);
      float4 av = *reinterpret_cast<const float4*>(agg + gw);
      float4 bv = *reinterpret_cast<const float4*>(b1 + (i4 & 63));
      z4.x = fmaxf(fmaf(e0, pv.x, av.x) + bv.x, 0.f);
      z4.y = fmaxf(fmaf(e0, pv.y, av.y) + bv.y, 0.f);
      z4.z = fmaxf(fmaf(e0, pv.z, av.z) + bv.z, 0.f);
      z4.w = fmaxf(fmaf(e0, pv.w, av.w) + bv.w, 0.f);
    }
    *reinterpret_cast<float4*>(Zs + i4) = z4;
  }
  __syncthreads();
  int j = t & 63, nl = t >> 6;
  float b2j = b2[j];
  float sj = g[j] * rsqrtf(var[j] + 1e-5f);
  float bj = be[j] - mu[j] * sj;
  float acc[16];
#pragma unroll
  for (int q = 0; q < 16; ++q) acc[q] = b2j;
  tile_gemm(Zs, W2s, nl, j, acc);
#pragma unroll
  for (int q = 0; q < 16; ++q) {
    int n = n0 + nl + q * 4;
    if (n < NN) out[n * HH + j] = fmaf(fmaxf(acc[q], 0.f), sj, bj);
  }
}

// -------- GIN layer MLP tile ----------------------------------------------
__global__ __launch_bounds__(256) void k_mlp_layer(
    const float* __restrict__ h, const float* __restrict__ agg,
    const float* __restrict__ epsv, const float* __restrict__ W1,
    const float* __restrict__ b1, const float* __restrict__ W2,
    const float* __restrict__ b2, const float* __restrict__ g,
    const float* __restrict__ be, const float* __restrict__ mu,
    const float* __restrict__ var, float* __restrict__ out) {
  __shared__ float Zs[HH * HH];
  __shared__ float W1s[HH * HH];
  __shared__ float W2s[HH * HH];
  int t = threadIdx.x;
  int n0 = blockIdx.x * 64;
  float e0 = 1.f + epsv[0];
  for (int i4 = t * 4; i4 < HH * HH; i4 += 1024) {
    *reinterpret_cast<float4*>(W1s + i4) =
        *reinterpret_cast<const float4*>(W1 + i4);
    *reinterpret_cast<float4*>(W2s + i4) =
        *reinterpret_cast<const float4*>(W2 + i4);
  }
  for (int i4 = t * 4; i4 < HH * HH; i4 += 1024) {
    int gw = n0 * HH + i4;
    float4 z4 = make_float4(0.f, 0.f, 0.f, 0.f);
    if (gw < NN * HH) {
      float4 hv = *reinterpret_cast<const float4*>(h + gw);
      float4 av = *reinterpret_cast<const float4*>(agg + gw);
      z4.x = fmaf(e0, hv.x, av.x);
      z4.y = fmaf(e0, hv.y, av.y);
      z4.z = fmaf(e0, hv.z, av.z);
      z4.w = fmaf(e0, hv.w, av.w);
    }
    *reinterpret_cast<float4*>(Zs + i4) = z4;
  }
  __syncthreads();
  int j = t & 63, nl = t >> 6;
  float b1j = b1[j], b2j = b2[j];
  float sj = g[j] * rsqrtf(var[j] + 1e-5f);
  float bj = be[j] - mu[j] * sj;
  float acc[16];
#pragma unroll
  for (int q = 0; q < 16; ++q) acc[q] = b1j;
  tile_gemm(Zs, W1s, nl, j, acc);
#pragma unroll
  for (int q = 0; q < 16; ++q) Zs[(nl + q * 4) * HH + j] = fmaxf(acc[q], 0.f);
#pragma unroll
  for (int q = 0; q < 16; ++q) acc[q] = b2j;
  tile_gemm(Zs, W2s, nl, j, acc);
#pragma unroll
  for (int q = 0; q < 16; ++q) {
    int n = n0 + nl + q * 4;
    if (n < NN) out[n * HH + j] = fmaf(fmaxf(acc[q], 0.f), sj, bj);
  }
}

// -------- readout tile: T=relu(h@L1+b1); o=T@L2+b2 -> log_softmax ----------
__global__ __launch_bounds__(256) void k_readout(
    const float* __restrict__ h, const float* __restrict__ W1,
    const float* __restrict__ b1, const float* __restrict__ W2,
    const float* __restrict__ b2, float* __restrict__ out) {
  __shared__ float Zs[HH * HH];
  __shared__ float W1s[HH * HH];
  __shared__ float W2s[HH * CC + 64];
  int t = threadIdx.x;
  int n0 = blockIdx.x * 64;
  for (int i4 = t * 4; i4 < HH * HH; i4 += 1024)
    *reinterpret_cast<float4*>(W1s + i4) =
        *reinterpret_cast<const float4*>(W1 + i4);
  for (int i = t; i < HH * CC + 64; i += 256)
    W2s[i] = (i < HH * CC) ? W2[i] : 0.f;
  for (int i4 = t * 4; i4 < HH * HH; i4 += 1024) {
    int gw = n0 * HH + i4;
    float4 z4 = make_float4(0.f, 0.f, 0.f, 0.f);
    if (gw < NN * HH) z4 = *reinterpret_cast<const float4*>(h + gw);
    *reinterpret_cast<float4*>(Zs + i4) = z4;
  }
  __syncthreads();
  int j = t & 63, nl = t >> 6;
  float b1j = b1[j];
  float b2j = (j < CC) ? b2[j] : 0.f;
  float acc[16];
#pragma unroll
  for (int q = 0; q < 16; ++q) acc[q] = b1j;
  tile_gemm(Zs, W1s, nl, j, acc);
#pragma unroll
  for (int q = 0; q < 16; ++q) Zs[(nl + q * 4) * HH + j] = fmaxf(acc[q], 0.f);
#pragma unroll
  for (int q = 0; q < 16; ++q) acc[q] = b2j;
  {
    const float4* Zv = reinterpret_cast<const float4*>(Zs);
    for (int k4 = 0; k4 < 16; ++k4) {
      float w0 = W2s[(k4 * 4 + 0) * CC + j];
      float w1 = W2s[(k4 * 4 + 1) * CC + j];
      float w2 = W2s[(k4 * 4 + 2) * CC + j];
      float w3 = W2s[(k4 * 4 + 3) * CC + j];
#pragma unroll
      for (int q = 0; q < 16; ++q) {
        float4 z = Zv[(nl + q * 4) * 16 + k4];
        acc[q] = fmaf(z.x, w0, acc[q]);
        acc[q] = fmaf(z.y, w1, acc[q]);
        acc[q] = fmaf(z.z, w2, acc[q]);
        acc[q] = fmaf(z.w, w3, acc[q]);
      }
    }
  }
#pragma unroll
  for (int q = 0; q < 16; ++q) {
    float o = acc[q];
    float om = (j < CC) ? o : -3.4e38f;
    float mx = om;
#pragma unroll
    for (int m = 32; m >= 1; m >>= 1) mx = fmaxf(mx, __shfl_xor(mx, m));
    float ex = (j < CC) ? expf(o - mx) : 0.f;
    float sm = ex;
#pragma unroll
    for (int m = 32; m >= 1; m >>= 1) sm += __shfl_xor(sm, m);
    int n = n0 + nl + q * 4;
    if (n < NN && j < CC) out[n * CC + j] = o - mx - logf(sm);
  }
}

extern "C" void kernel_launch(void* const* d_in, const int* in_sizes, int n_in,
                              void* d_out, int out_size, void* d_ws,
                              size_t ws_size, hipStream_t stream) {
  const float* x = (const float*)d_in[0];
  const int* ei = (const int*)d_in[1];
  const float* eps = (const float*)d_in[2];
  const float* fW1 = (const float*)d_in[3];
  const float* fb1 = (const float*)d_in[4];
  const float* fW2 = (const float*)d_in[5];
  const float* fb2 = (const float*)d_in[6];
  const float* W1s = (const float*)d_in[7];
  const float* b1s = (const float*)d_in[8];
  const float* W2s = (const float*)d_in[9];
  const float* b2s = (const float*)d_in[10];
  const float* bn_g = (const float*)d_in[11];
  const float* bn_b = (const float*)d_in[12];
  const float* bn_m = (const float*)d_in[13];
  const float* bn_v = (const float*)d_in[14];
  const float* l1W = (const float*)d_in[15];
  const float* l1b = (const float*)d_in[16];
  const float* l2W = (const float*)d_in[17];
  const float* l2b = (const float*)d_in[18];
  float* out = (float*)d_out;

  // ws: eidx[EE] | rowptr[NN+1] | pad | buf0 | buf1(agg) | buf2
  // counts/cursor overlay buf1 (dead before first k_gather writes buf1);
  // buf0 (p) is written concurrently with counts by the fat kernel.
  int* eidx = (int*)d_ws;
  int* rowptr = eidx + EE;
  size_t int_elems = (size_t)EE + NN + 1;
  size_t f_off = (int_elems + 3) & ~(size_t)3;
  const size_t NH = (size_t)NN * HH;
  float* buf0 = (float*)d_ws + f_off;  // p / h
  float* buf1 = buf0 + NH;             // agg
  float* buf2 = buf1 + NH;             // h alt
  int* counts = (int*)buf1;            // overlay, dead after k_rowptr
  int* cursor = counts + NN;           // overlay, dead after k_fill

  hipMemsetAsync(counts, 0, NN * sizeof(int), stream);
  // fat kernel: gemm_first (blocks 0..TB) + degree count (TB..TB+CNTB)
  k_gemm_count<<<TB + CNTB, 256, 0, stream>>>(x, fW1, buf0, ei, counts);
  k_rowptr<<<RPB, 256, 0, stream>>>(counts, rowptr, cursor);
  k_fill<<<(EE / 4 + 255) / 256, 256, 0, stream>>>(ei, cursor, eidx);

  // first conv
  k_gather<<<(NN + 15) / 16, 256, 0, stream>>>(buf0, rowptr, eidx, buf1);
  k_mlp_first<<<TB, 256, 0, stream>>>(buf0, buf1, eps + 0, fb1, fW2, fb2,
                                      bn_g, bn_b, bn_m, bn_v, buf2);
  // layer 0
  k_gather<<<(NN + 15) / 16, 256, 0, stream>>>(buf2, rowptr, eidx, buf1);
  k_mlp_layer<<<TB, 256, 0, stream>>>(buf2, buf1, eps + 1, W1s, b1s, W2s,
                                      b2s, bn_g + HH, bn_b + HH, bn_m + HH,
                                      bn_v + HH, buf0);
  // layer 1
  k_gather<<<(NN + 15) / 16, 256, 0, stream>>>(buf0, rowptr, eidx, buf1);
  k_mlp_layer<<<TB, 256, 0, stream>>>(buf0, buf1, eps + 2, W1s + HH * HH,
                                      b1s + HH, W2s + HH * HH, b2s + HH,
                                      bn_g + 2 * HH, bn_b + 2 * HH,
                                      bn_m + 2 * HH, bn_v + 2 * HH, buf2);
  // readout
  k_readout<<<TB, 256, 0, stream>>>(buf2, l1W, l1b, l2W, l2b, out);
}

// Round 8
// 409.782 us; speedup vs baseline: 1.1756x; 1.1756x over previous
//
#include <hip/hip_runtime.h>
#include <math.h>

#define NN 50000
#define EE 800000
#define FIN 100
#define HH 64
#define CC 18
#define PD 68   // padded LDS row stride (floats): 68%32=4 -> 2-way max
#define TB 782  // ceil(NN/64)
#define NB 49   // ceil(NN/1024)

// ---------------- CSR: degree count ----------------------------------------
__global__ __launch_bounds__(256) void k_count(const int* __restrict__ ei,
                                               int* __restrict__ counts) {
  for (int e = blockIdx.x * 256 + threadIdx.x; e < EE; e += gridDim.x * 256)
    atomicAdd(&counts[ei[EE + e]], 1);
}

__device__ __forceinline__ void load4_guard(const int* __restrict__ a, int i4,
                                            int& c0, int& c1, int& c2,
                                            int& c3) {
  if (i4 + 3 < NN) {
    int4 v = *reinterpret_cast<const int4*>(a + i4);
    c0 = v.x; c1 = v.y; c2 = v.z; c3 = v.w;
  } else {
    c0 = (i4 < NN) ? a[i4] : 0;
    c1 = (i4 + 1 < NN) ? a[i4 + 1] : 0;
    c2 = (i4 + 2 < NN) ? a[i4 + 2] : 0;
    c3 = (i4 + 3 < NN) ? a[i4 + 3] : 0;
  }
}

// phase 1: per-block sums of 1024 counts
__global__ __launch_bounds__(256) void k_bsum(const int* __restrict__ counts,
                                              int* __restrict__ bsum) {
  __shared__ int ws[4];
  int t = threadIdx.x, lane = t & 63, wid = t >> 6;
  int i4 = blockIdx.x * 1024 + t * 4;
  int c0, c1, c2, c3;
  load4_guard(counts, i4, c0, c1, c2, c3);
  int s = c0 + c1 + c2 + c3;
#pragma unroll
  for (int m = 32; m >= 1; m >>= 1) s += __shfl_xor(s, m);
  if (lane == 0) ws[wid] = s;
  __syncthreads();
  if (t == 0) bsum[blockIdx.x] = ws[0] + ws[1] + ws[2] + ws[3];
}

// phase 2: single wave scans NB block sums -> exclusive offsets + total
__global__ __launch_bounds__(64) void k_bscan(const int* __restrict__ bsum,
                                              int* __restrict__ boff,
                                              int* __restrict__ rowptr) {
  int lane = threadIdx.x;
  int v = (lane < NB) ? bsum[lane] : 0;
  int x = v;
#pragma unroll
  for (int off = 1; off < 64; off <<= 1) {
    int y = __shfl_up(x, off);
    if (lane >= off) x += y;
  }
  if (lane < NB) boff[lane] = x - v;
  if (lane == NB - 1) rowptr[NN] = x;
}

// phase 3: per-block exclusive prefix -> rowptr & cursor
__global__ __launch_bounds__(256) void k_rowptr(const int* __restrict__ counts,
                                                const int* __restrict__ boff,
                                                int* __restrict__ rowptr,
                                                int* __restrict__ cursor) {
  __shared__ int wtot[4];
  int t = threadIdx.x, lane = t & 63, wid = t >> 6;
  int i4 = blockIdx.x * 1024 + t * 4;
  int c0, c1, c2, c3;
  load4_guard(counts, i4, c0, c1, c2, c3);
  int s = c0 + c1 + c2 + c3;
  int x = s;
#pragma unroll
  for (int off = 1; off < 64; off <<= 1) {
    int y = __shfl_up(x, off);
    if (lane >= off) x += y;
  }
  if (lane == 63) wtot[wid] = x;
  __syncthreads();
  int base = boff[blockIdx.x];
  for (int w = 0; w < wid; ++w) base += wtot[w];
  int p = base + x - s;  // exclusive prefix for this thread's 4 elems
  int p0 = p, p1 = p0 + c0, p2 = p1 + c1, p3 = p2 + c2;
  if (i4 + 3 < NN) {
    *reinterpret_cast<int4*>(rowptr + i4) = make_int4(p0, p1, p2, p3);
    *reinterpret_cast<int4*>(cursor + i4) = make_int4(p0, p1, p2, p3);
  } else {
    if (i4 < NN) { rowptr[i4] = p0; cursor[i4] = p0; }
    if (i4 + 1 < NN) { rowptr[i4 + 1] = p1; cursor[i4 + 1] = p1; }
    if (i4 + 2 < NN) { rowptr[i4 + 2] = p2; cursor[i4 + 2] = p2; }
  }
}

// ---- fill: eidx[pos] = src ------------------------------------------------
__global__ __launch_bounds__(256) void k_fill(const int* __restrict__ ei,
                                              int* __restrict__ cursor,
                                              int* __restrict__ eidx) {
  int e4 = (blockIdx.x * 256 + threadIdx.x) * 4;
  if (e4 >= EE) return;
  int4 sv = *reinterpret_cast<const int4*>(ei + e4);
  int4 dv = *reinterpret_cast<const int4*>(ei + EE + e4);
  eidx[atomicAdd(&cursor[dv.x], 1)] = sv.x;
  eidx[atomicAdd(&cursor[dv.y], 1)] = sv.y;
  eidx[atomicAdd(&cursor[dv.z], 1)] = sv.z;
  eidx[atomicAdd(&cursor[dv.w], 1)] = sv.w;
}

// ---- gather fused with GIN pre-sum: z[n] = (1+eps)*feat[n] + sum feat[src]
__global__ __launch_bounds__(256) void k_gather(
    const float* __restrict__ feat, const int* __restrict__ rowptr,
    const int* __restrict__ eidx, const float* __restrict__ epsv,
    float* __restrict__ zout) {
  int t = threadIdx.x;
  int grp = t >> 4, c4 = t & 15;
  int n = blockIdx.x * 16 + grp;
  if (n >= NN) return;
  float e0 = 1.f + epsv[0];
  int beg = rowptr[n], end = rowptr[n + 1];
  const float* fp = feat + c4 * 4;
  float4 self = *reinterpret_cast<const float4*>(fp + n * HH);
  float ax = e0 * self.x, ay = e0 * self.y, az = e0 * self.z,
        aw = e0 * self.w;
  int i = beg;
  for (; i + 8 <= end; i += 8) {
    int s0 = eidx[i + 0], s1 = eidx[i + 1], s2 = eidx[i + 2],
        s3 = eidx[i + 3], s4 = eidx[i + 4], s5 = eidx[i + 5],
        s6 = eidx[i + 6], s7 = eidx[i + 7];
    float4 v0 = *reinterpret_cast<const float4*>(fp + s0 * HH);
    float4 v1 = *reinterpret_cast<const float4*>(fp + s1 * HH);
    float4 v2 = *reinterpret_cast<const float4*>(fp + s2 * HH);
    float4 v3 = *reinterpret_cast<const float4*>(fp + s3 * HH);
    float4 v4 = *reinterpret_cast<const float4*>(fp + s4 * HH);
    float4 v5 = *reinterpret_cast<const float4*>(fp + s5 * HH);
    float4 v6 = *reinterpret_cast<const float4*>(fp + s6 * HH);
    float4 v7 = *reinterpret_cast<const float4*>(fp + s7 * HH);
    ax += ((v0.x + v1.x) + (v2.x + v3.x)) + ((v4.x + v5.x) + (v6.x + v7.x));
    ay += ((v0.y + v1.y) + (v2.y + v3.y)) + ((v4.y + v5.y) + (v6.y + v7.y));
    az += ((v0.z + v1.z) + (v2.z + v3.z)) + ((v4.z + v5.z) + (v6.z + v7.z));
    aw += ((v0.w + v1.w) + (v2.w + v3.w)) + ((v4.w + v5.w) + (v6.w + v7.w));
  }
  for (; i < end; ++i) {
    float4 v = *reinterpret_cast<const float4*>(fp + eidx[i] * HH);
    ax += v.x; ay += v.y; az += v.z; aw += v.w;
  }
  *reinterpret_cast<float4*>(zout + n * HH + c4 * 4) =
      make_float4(ax, ay, az, aw);
}

// ---- 4x4 register-tile FMA ------------------------------------------------
__device__ __forceinline__ void fma4(float4& a, const float4 z,
                                     const float4 w0, const float4 w1,
                                     const float4 w2, const float4 w3) {
  a.x = fmaf(z.x, w0.x, a.x); a.x = fmaf(z.y, w1.x, a.x);
  a.x = fmaf(z.z, w2.x, a.x); a.x = fmaf(z.w, w3.x, a.x);
  a.y = fmaf(z.x, w0.y, a.y); a.y = fmaf(z.y, w1.y, a.y);
  a.y = fmaf(z.z, w2.y, a.y); a.y = fmaf(z.w, w3.y, a.y);
  a.z = fmaf(z.x, w0.z, a.z); a.z = fmaf(z.y, w1.z, a.z);
  a.z = fmaf(z.z, w2.z, a.z); a.z = fmaf(z.w, w3.z, a.z);
  a.w = fmaf(z.x, w0.w, a.w); a.w = fmaf(z.y, w1.w, a.w);
  a.w = fmaf(z.z, w2.w, a.w); a.w = fmaf(z.w, w3.w, a.w);
}

// 64x64 gemm main loop: Zs padded stride PD, Ws stride HH
__device__ __forceinline__ void gemm_rc(const float* __restrict__ Zs,
                                        const float* __restrict__ Ws, int c4,
                                        int nl, float4 acc[4]) {
  for (int k4 = 0; k4 < 16; ++k4) {
    float4 w0 = *reinterpret_cast<const float4*>(Ws + (k4 * 4 + 0) * HH + c4 * 4);
    float4 w1 = *reinterpret_cast<const float4*>(Ws + (k4 * 4 + 1) * HH + c4 * 4);
    float4 w2 = *reinterpret_cast<const float4*>(Ws + (k4 * 4 + 2) * HH + c4 * 4);
    float4 w3 = *reinterpret_cast<const float4*>(Ws + (k4 * 4 + 3) * HH + c4 * 4);
#pragma unroll
    for (int q = 0; q < 4; ++q) {
      float4 z = *reinterpret_cast<const float4*>(Zs + (nl * 4 + q) * PD + k4 * 4);
      fma4(acc[q], z, w0, w1, w2, w3);
    }
  }
}

// ---- p = x @ fW1 (4x4 register tile) --------------------------------------
__global__ __launch_bounds__(256) void k_gemm_first(
    const float* __restrict__ x, const float* __restrict__ W,
    float* __restrict__ p) {
  __shared__ float Ws[FIN * HH];   // 25.6 KB
  __shared__ float xs[64 * FIN];   // 25.6 KB
  int t = threadIdx.x;
  int n0 = blockIdx.x * 64;
  for (int i4 = t * 4; i4 < FIN * HH; i4 += 1024)
    *reinterpret_cast<float4*>(Ws + i4) =
        *reinterpret_cast<const float4*>(W + i4);
  for (int i4 = t * 4; i4 < 64 * FIN; i4 += 1024) {
    int r = i4 / FIN, c = i4 - r * FIN;  // FIN%4==0 -> c%4==0
    int n = n0 + r;
    float4 v = make_float4(0.f, 0.f, 0.f, 0.f);
    if (n < NN) v = *reinterpret_cast<const float4*>(x + n * FIN + c);
    *reinterpret_cast<float4*>(xs + i4) = v;
  }
  __syncthreads();
  int c4 = t & 15, nl = t >> 4;
  float4 acc[4];
#pragma unroll
  for (int q = 0; q < 4; ++q) acc[q] = make_float4(0.f, 0.f, 0.f, 0.f);
  for (int k4 = 0; k4 < FIN / 4; ++k4) {
    float4 w0 = *reinterpret_cast<const float4*>(Ws + (k4 * 4 + 0) * HH + c4 * 4);
    float4 w1 = *reinterpret_cast<const float4*>(Ws + (k4 * 4 + 1) * HH + c4 * 4);
    float4 w2 = *reinterpret_cast<const float4*>(Ws + (k4 * 4 + 2) * HH + c4 * 4);
    float4 w3 = *reinterpret_cast<const float4*>(Ws + (k4 * 4 + 3) * HH + c4 * 4);
#pragma unroll
    for (int q = 0; q < 4; ++q) {
      float4 z = *reinterpret_cast<const float4*>(xs + (nl * 4 + q) * FIN + k4 * 4);
      fma4(acc[q], z, w0, w1, w2, w3);
    }
  }
#pragma unroll
  for (int q = 0; q < 4; ++q) {
    int n = n0 + nl * 4 + q;
    if (n < NN) *reinterpret_cast<float4*>(p + n * HH + c4 * 4) = acc[q];
  }
}

// ---- first conv MLP: T=relu(z+b1) staged; out = BN(relu(T@W2+b2)) ---------
__global__ __launch_bounds__(256) void k_mlp_first(
    const float* __restrict__ zbuf, const float* __restrict__ b1,
    const float* __restrict__ W2, const float* __restrict__ b2,
    const float* __restrict__ g, const float* __restrict__ be,
    const float* __restrict__ mu, const float* __restrict__ var,
    float* __restrict__ out) {
  __shared__ float Zs[64 * PD];
  __shared__ float W2s[HH * HH];
  int t = threadIdx.x;
  int n0 = blockIdx.x * 64;
  for (int i4 = t * 4; i4 < HH * HH; i4 += 1024)
    *reinterpret_cast<float4*>(W2s + i4) =
        *reinterpret_cast<const float4*>(W2 + i4);
  for (int i4 = t * 4; i4 < HH * HH; i4 += 1024) {
    int r = i4 >> 6, c = i4 & 63;
    int n = n0 + r;
    float4 z4 = make_float4(0.f, 0.f, 0.f, 0.f);
    if (n < NN) {
      float4 zv = *reinterpret_cast<const float4*>(zbuf + n * HH + c);
      float4 bv = *reinterpret_cast<const float4*>(b1 + c);
      z4.x = fmaxf(zv.x + bv.x, 0.f);
      z4.y = fmaxf(zv.y + bv.y, 0.f);
      z4.z = fmaxf(zv.z + bv.z, 0.f);
      z4.w = fmaxf(zv.w + bv.w, 0.f);
    }
    *reinterpret_cast<float4*>(Zs + r * PD + c) = z4;
  }
  __syncthreads();
  int c4 = t & 15, nl = t >> 4;
  float4 b2v = *reinterpret_cast<const float4*>(b2 + c4 * 4);
  float4 acc[4];
#pragma unroll
  for (int q = 0; q < 4; ++q) acc[q] = b2v;
  gemm_rc(Zs, W2s, c4, nl, acc);
  float4 gv = *reinterpret_cast<const float4*>(g + c4 * 4);
  float4 bev = *reinterpret_cast<const float4*>(be + c4 * 4);
  float4 muv = *reinterpret_cast<const float4*>(mu + c4 * 4);
  float4 vav = *reinterpret_cast<const float4*>(var + c4 * 4);
  float4 sj, bj;
  sj.x = gv.x * rsqrtf(vav.x + 1e-5f); bj.x = bev.x - muv.x * sj.x;
  sj.y = gv.y * rsqrtf(vav.y + 1e-5f); bj.y = bev.y - muv.y * sj.y;
  sj.z = gv.z * rsqrtf(vav.z + 1e-5f); bj.z = bev.z - muv.z * sj.z;
  sj.w = gv.w * rsqrtf(vav.w + 1e-5f); bj.w = bev.w - muv.w * sj.w;
#pragma unroll
  for (int q = 0; q < 4; ++q) {
    int n = n0 + nl * 4 + q;
    if (n < NN) {
      float4 o;
      o.x = fmaf(fmaxf(acc[q].x, 0.f), sj.x, bj.x);
      o.y = fmaf(fmaxf(acc[q].y, 0.f), sj.y, bj.y);
      o.z = fmaf(fmaxf(acc[q].z, 0.f), sj.z, bj.z);
      o.w = fmaf(fmaxf(acc[q].w, 0.f), sj.w, bj.w);
      *reinterpret_cast<float4*>(out + n * HH + c4 * 4) = o;
    }
  }
}

// ---- GIN layer MLP: T=relu(z@W1+b1) (barriered); out = BN(relu(T@W2+b2)) --
__global__ __launch_bounds__(256) void k_mlp_layer(
    const float* __restrict__ zbuf, const float* __restrict__ W1,
    const float* __restrict__ b1, const float* __restrict__ W2,
    const float* __restrict__ b2, const float* __restrict__ g,
    const float* __restrict__ be, const float* __restrict__ mu,
    const float* __restrict__ var, float* __restrict__ out) {
  __shared__ float Zs[64 * PD];
  __shared__ float W1s[HH * HH];
  __shared__ float W2s[HH * HH];
  int t = threadIdx.x;
  int n0 = blockIdx.x * 64;
  for (int i4 = t * 4; i4 < HH * HH; i4 += 1024) {
    *reinterpret_cast<float4*>(W1s + i4) =
        *reinterpret_cast<const float4*>(W1 + i4);
    *reinterpret_cast<float4*>(W2s + i4) =
        *reinterpret_cast<const float4*>(W2 + i4);
  }
  for (int i4 = t * 4; i4 < HH * HH; i4 += 1024) {
    int r = i4 >> 6, c = i4 & 63;
    int n = n0 + r;
    float4 z4 = make_float4(0.f, 0.f, 0.f, 0.f);
    if (n < NN) z4 = *reinterpret_cast<const float4*>(zbuf + n * HH + c);
    *reinterpret_cast<float4*>(Zs + r * PD + c) = z4;
  }
  __syncthreads();
  int c4 = t & 15, nl = t >> 4;
  float4 b1v = *reinterpret_cast<const float4*>(b1 + c4 * 4);
  float4 acc[4];
#pragma unroll
  for (int q = 0; q < 4; ++q) acc[q] = b1v;
  gemm_rc(Zs, W1s, c4, nl, acc);
  // barriered T writeback (R7's barrier-free version tripped the graph
  // replay tripwire; two extra barriers per block are negligible here)
  __syncthreads();
#pragma unroll
  for (int q = 0; q < 4; ++q) {
    float4 tq;
    tq.x = fmaxf(acc[q].x, 0.f); tq.y = fmaxf(acc[q].y, 0.f);
    tq.z = fmaxf(acc[q].z, 0.f); tq.w = fmaxf(acc[q].w, 0.f);
    *reinterpret_cast<float4*>(Zs + (nl * 4 + q) * PD + c4 * 4) = tq;
  }
  __syncthreads();
  float4 b2v = *reinterpret_cast<const float4*>(b2 + c4 * 4);
#pragma unroll
  for (int q = 0; q < 4; ++q) acc[q] = b2v;
  gemm_rc(Zs, W2s, c4, nl, acc);
  float4 gv = *reinterpret_cast<const float4*>(g + c4 * 4);
  float4 bev = *reinterpret_cast<const float4*>(be + c4 * 4);
  float4 muv = *reinterpret_cast<const float4*>(mu + c4 * 4);
  float4 vav = *reinterpret_cast<const float4*>(var + c4 * 4);
  float4 sj, bj;
  sj.x = gv.x * rsqrtf(vav.x + 1e-5f); bj.x = bev.x - muv.x * sj.x;
  sj.y = gv.y * rsqrtf(vav.y + 1e-5f); bj.y = bev.y - muv.y * sj.y;
  sj.z = gv.z * rsqrtf(vav.z + 1e-5f); bj.z = bev.z - muv.z * sj.z;
  sj.w = gv.w * rsqrtf(vav.w + 1e-5f); bj.w = bev.w - muv.w * sj.w;
#pragma unroll
  for (int q = 0; q < 4; ++q) {
    int n = n0 + nl * 4 + q;
    if (n < NN) {
      float4 o;
      o.x = fmaf(fmaxf(acc[q].x, 0.f), sj.x, bj.x);
      o.y = fmaf(fmaxf(acc[q].y, 0.f), sj.y, bj.y);
      o.z = fmaf(fmaxf(acc[q].z, 0.f), sj.z, bj.z);
      o.w = fmaf(fmaxf(acc[q].w, 0.f), sj.w, bj.w);
      *reinterpret_cast<float4*>(out + n * HH + c4 * 4) = o;
    }
  }
}

// ---- readout: T=relu(h@L1+b1) (barriered); o=T@L2+b2 -> log_softmax -------
__global__ __launch_bounds__(256) void k_readout(
    const float* __restrict__ h, const float* __restrict__ W1,
    const float* __restrict__ b1, const float* __restrict__ W2,
    const float* __restrict__ b2, float* __restrict__ out) {
  __shared__ float Zs[64 * PD];
  __shared__ float W1s[HH * HH];
  __shared__ float W2s[HH * CC + 64];
  int t = threadIdx.x;
  int n0 = blockIdx.x * 64;
  for (int i4 = t * 4; i4 < HH * HH; i4 += 1024)
    *reinterpret_cast<float4*>(W1s + i4) =
        *reinterpret_cast<const float4*>(W1 + i4);
  for (int i = t; i < HH * CC + 64; i += 256)
    W2s[i] = (i < HH * CC) ? W2[i] : 0.f;
  for (int i4 = t * 4; i4 < HH * HH; i4 += 1024) {
    int r = i4 >> 6, c = i4 & 63;
    int n = n0 + r;
    float4 z4 = make_float4(0.f, 0.f, 0.f, 0.f);
    if (n < NN) z4 = *reinterpret_cast<const float4*>(h + n * HH + c);
    *reinterpret_cast<float4*>(Zs + r * PD + c) = z4;
  }
  __syncthreads();
  int j = t & 63, nl = t >> 6;
  float b1j = b1[j];
  float b2j = (j < CC) ? b2[j] : 0.f;
  float acc[16];
#pragma unroll
  for (int q = 0; q < 16; ++q) acc[q] = b1j;
  for (int k4 = 0; k4 < 16; ++k4) {
    float w0 = W1s[(k4 * 4 + 0) * HH + j];
    float w1 = W1s[(k4 * 4 + 1) * HH + j];
    float w2 = W1s[(k4 * 4 + 2) * HH + j];
    float w3 = W1s[(k4 * 4 + 3) * HH + j];
#pragma unroll
    for (int q = 0; q < 16; ++q) {
      float4 z = *reinterpret_cast<const float4*>(Zs + (nl + q * 4) * PD + k4 * 4);
      acc[q] = fmaf(z.x, w0, acc[q]);
      acc[q] = fmaf(z.y, w1, acc[q]);
      acc[q] = fmaf(z.z, w2, acc[q]);
      acc[q] = fmaf(z.w, w3, acc[q]);
    }
  }
  __syncthreads();
#pragma unroll
  for (int q = 0; q < 16; ++q)
    Zs[(nl + q * 4) * PD + j] = fmaxf(acc[q], 0.f);
  __syncthreads();
#pragma unroll
  for (int q = 0; q < 16; ++q) acc[q] = b2j;
  for (int k4 = 0; k4 < 16; ++k4) {
    float w0 = W2s[(k4 * 4 + 0) * CC + j];
    float w1 = W2s[(k4 * 4 + 1) * CC + j];
    float w2 = W2s[(k4 * 4 + 2) * CC + j];
    float w3 = W2s[(k4 * 4 + 3) * CC + j];
#pragma unroll
    for (int q = 0; q < 16; ++q) {
      float4 z = *reinterpret_cast<const float4*>(Zs + (nl + q * 4) * PD + k4 * 4);
      acc[q] = fmaf(z.x, w0, acc[q]);
      acc[q] = fmaf(z.y, w1, acc[q]);
      acc[q] = fmaf(z.z, w2, acc[q]);
      acc[q] = fmaf(z.w, w3, acc[q]);
    }
  }
#pragma unroll
  for (int q = 0; q < 16; ++q) {
    float o = acc[q];
    float om = (j < CC) ? o : -3.4e38f;
    float mx = om;
#pragma unroll
    for (int m = 32; m >= 1; m >>= 1) mx = fmaxf(mx, __shfl_xor(mx, m));
    float ex = (j < CC) ? expf(o - mx) : 0.f;
    float sm = ex;
#pragma unroll
    for (int m = 32; m >= 1; m >>= 1) sm += __shfl_xor(sm, m);
    int n = n0 + nl + q * 4;
    if (n < NN && j < CC) out[n * CC + j] = o - mx - logf(sm);
  }
}

extern "C" void kernel_launch(void* const* d_in, const int* in_sizes, int n_in,
                              void* d_out, int out_size, void* d_ws,
                              size_t ws_size, hipStream_t stream) {
  const float* x = (const float*)d_in[0];
  const int* ei = (const int*)d_in[1];
  const float* eps = (const float*)d_in[2];
  const float* fW1 = (const float*)d_in[3];
  const float* fb1 = (const float*)d_in[4];
  const float* fW2 = (const float*)d_in[5];
  const float* fb2 = (const float*)d_in[6];
  const float* W1s = (const float*)d_in[7];
  const float* b1s = (const float*)d_in[8];
  const float* W2s = (const float*)d_in[9];
  const float* b2s = (const float*)d_in[10];
  const float* bn_g = (const float*)d_in[11];
  const float* bn_b = (const float*)d_in[12];
  const float* bn_m = (const float*)d_in[13];
  const float* bn_v = (const float*)d_in[14];
  const float* l1W = (const float*)d_in[15];
  const float* l1b = (const float*)d_in[16];
  const float* l2W = (const float*)d_in[17];
  const float* l2b = (const float*)d_in[18];
  float* out = (float*)d_out;

  // ws: eidx[EE] | rowptr[NN+1] | boff[NB] | bsum[NB] | pad |
  //     buf0(p/h) | buf1(z) | buf2(h alt)
  // counts/cursor overlay buf1 (dead before first k_gather writes buf1)
  int* eidx = (int*)d_ws;
  int* rowptr = eidx + EE;
  int* boff = rowptr + NN + 1;
  int* bsum = boff + NB;
  size_t int_elems = (size_t)EE + NN + 1 + 2 * NB;
  size_t f_off = (int_elems + 3) & ~(size_t)3;
  const size_t NH = (size_t)NN * HH;
  float* buf0 = (float*)d_ws + f_off;
  float* buf1 = buf0 + NH;
  float* buf2 = buf1 + NH;
  int* counts = (int*)buf1;
  int* cursor = counts + NN;

  // CSR build (R6-proven chain)
  hipMemsetAsync(counts, 0, NN * sizeof(int), stream);
  k_count<<<2048, 256, 0, stream>>>(ei, counts);
  k_bsum<<<NB, 256, 0, stream>>>(counts, bsum);
  k_bscan<<<1, 64, 0, stream>>>(bsum, boff, rowptr);
  k_rowptr<<<NB, 256, 0, stream>>>(counts, boff, rowptr, cursor);
  k_fill<<<(EE / 4 + 255) / 256, 256, 0, stream>>>(ei, cursor, eidx);

  // p = x @ fW1
  k_gemm_first<<<TB, 256, 0, stream>>>(x, fW1, buf0);

  // first conv: z=(1+e)p + gather(p) -> buf1 ; MLP -> buf2 (h0)
  k_gather<<<(NN + 15) / 16, 256, 0, stream>>>(buf0, rowptr, eidx, eps + 0,
                                               buf1);
  k_mlp_first<<<TB, 256, 0, stream>>>(buf1, fb1, fW2, fb2, bn_g, bn_b, bn_m,
                                      bn_v, buf2);
  // layer 0: buf2 -> buf0
  k_gather<<<(NN + 15) / 16, 256, 0, stream>>>(buf2, rowptr, eidx, eps + 1,
                                               buf1);
  k_mlp_layer<<<TB, 256, 0, stream>>>(buf1, W1s, b1s, W2s, b2s, bn_g + HH,
                                      bn_b + HH, bn_m + HH, bn_v + HH, buf0);
  // layer 1: buf0 -> buf2
  k_gather<<<(NN + 15) / 16, 256, 0, stream>>>(buf0, rowptr, eidx, eps + 2,
                                               buf1);
  k_mlp_layer<<<TB, 256, 0, stream>>>(buf1, W1s + HH * HH, b1s + HH,
                                      W2s + HH * HH, b2s + HH, bn_g + 2 * HH,
                                      bn_b + 2 * HH, bn_m + 2 * HH,
                                      bn_v + 2 * HH, buf2);
  // readout
  k_readout<<<TB, 256, 0, stream>>>(buf2, l1W, l1b, l2W, l2b, out);
}